// Round 8
// baseline (1043.051 us; speedup 1.0000x reference)
//
#include <hip/hip_runtime.h>

#define BATCH   64
#define CHANS   36
#define ANCH    8400
#define NCLS    32
#define MAXDET  100
#define CONF    0.25f
#define KTOP    256             // matrix region (bucket-aligned cutoff K <= KTOP)
#define NBUCK   256
#define BUCK0   16000u          // (0x3E800000 >> 16): 64Ki-ulp buckets over [0.25, 1.0)
#define PBLK    33              // prep blocks per image (ceil(2100/64))

typedef unsigned long long u64;
typedef unsigned int       u32;

// exact ref IoU-threshold compare: for uni>0, RN(inter/uni) > 0.45f <=> inter > M*uni
// (a = suppressor box, matching reference op order; f32 ops, no contraction)
__device__ __forceinline__ bool iou_gt(float ay1, float ax1, float ay2, float ax2, float aar,
                                       float by1, float bx1, float by2, float bx2, float bar,
                                       double M) {
#pragma clang fp contract(off)
    float iy1 = fmaxf(ay1, by1), ix1 = fmaxf(ax1, bx1);
    float iy2 = fminf(ay2, by2), ix2 = fminf(ax2, bx2);
    float inter = fmaxf(iy2 - iy1, 0.f) * fmaxf(ix2 - ix1, 0.f);
    float uni = (aar + bar) - inter;
    return (double)inter > M * (double)uni;
}

// recompute clipped corner box for anchor a (bit-identical to reference)
__device__ __forceinline__ float4 load_box(const float* __restrict__ inb, int a) {
#pragma clang fp contract(off)
    float xc = inb[0 * ANCH + a], yc = inb[1 * ANCH + a];
    float w  = inb[2 * ANCH + a], h  = inb[3 * ANCH + a];
    float4 r;
    r.x = fminf(fmaxf(yc - h * 0.5f, 0.f), 1.f);
    r.y = fminf(fmaxf(xc - w * 0.5f, 0.f), 1.f);
    r.z = fminf(fmaxf(yc + h * 0.5f, 0.f), 1.f);
    r.w = fminf(fmaxf(xc + w * 0.5f, 0.f), 1.f);
    return r;
}

// ---------------- Phase A: prep, 4 threads per float4-anchor-group ----------------
// Lane layout: sub = lane&15 selects group-in-16, q = lane>>4 selects the 8-class
// quarter. xor-shuffles over lane bits 16/32 keep g fixed and combine quarters.
// 2112 blocks -> ~33 waves/CU; 8-12 independent loads per thread in one window.
__global__ __launch_bounds__(256) void yolo_prep(const float* __restrict__ in,
                                                 u64* __restrict__ wk64,
                                                 u32* __restrict__ histp) {
#pragma clang fp contract(off)
    const int G = ANCH / 4;             // 2100
    int t = threadIdx.x, b = blockIdx.y;
    int lane = t & 63, wv = t >> 6;
    int sub = lane & 15, q = lane >> 4;
    int g = blockIdx.x * 64 + wv * 16 + sub;
    bool act = (g < G);

    __shared__ u32 lh[NBUCK];
    for (int i = t; i < NBUCK; i += 256) lh[i] = 0u;
    __syncthreads();

    const float4* p = (const float4*)(in + (size_t)b * (CHANS * ANCH));
    float4 bs = make_float4(-1e30f, -1e30f, -1e30f, -1e30f);
    uint4  bc = make_uint4(0, 0, 0, 0);
    float4 xc4, yc4, ww4, hh4;
    if (act) {
        int c0 = q * 8;
        bs = p[(4 + c0) * G + g];
        bc = make_uint4((u32)c0, (u32)c0, (u32)c0, (u32)c0);
#pragma unroll
        for (int k = 1; k < 8; ++k) {
            float4 v = p[(4 + c0 + k) * G + g];
            u32 c = (u32)(c0 + k);
            if (v.x > bs.x) { bs.x = v.x; bc.x = c; }   // strict >: first index (np.argmax)
            if (v.y > bs.y) { bs.y = v.y; bc.y = c; }
            if (v.z > bs.z) { bs.z = v.z; bc.z = c; }
            if (v.w > bs.w) { bs.w = v.w; bc.w = c; }
        }
        if (q == 0) {
            xc4 = p[0 * G + g]; yc4 = p[1 * G + g];
            ww4 = p[2 * G + g]; hh4 = p[3 * G + g];
        }
    }
    (void)xc4; (void)yc4; (void)ww4; (void)hh4;   // boxes recomputed downstream; loads kept out

    // combine quarters: prefer higher score; tie -> lower class index (argmax-first)
#pragma unroll
    for (int d = 16; d < 64; d <<= 1) {
        float sx = __shfl_xor(bs.x, d, 64); u32 cx = __shfl_xor(bc.x, d, 64);
        float sy = __shfl_xor(bs.y, d, 64); u32 cy = __shfl_xor(bc.y, d, 64);
        float sz = __shfl_xor(bs.z, d, 64); u32 cz = __shfl_xor(bc.z, d, 64);
        float sw = __shfl_xor(bs.w, d, 64); u32 cw = __shfl_xor(bc.w, d, 64);
        if (sx > bs.x || (sx == bs.x && cx < bc.x)) { bs.x = sx; bc.x = cx; }
        if (sy > bs.y || (sy == bs.y && cy < bc.y)) { bs.y = sy; bc.y = cy; }
        if (sz > bs.z || (sz == bs.z && cz < bc.z)) { bs.z = sz; bc.z = cz; }
        if (sw > bs.w || (sw == bs.w && cw < bc.w)) { bs.w = sw; bc.w = cw; }
    }

    if (act && q == 0) {
        u64 kv[4];
#define KEY_C(C, I)                                                           \
        {                                                                     \
            kv[I] = 0ull;                                                     \
            if (bs.C >= CONF) {                                               \
                u32 sb = __float_as_uint(bs.C);                               \
                kv[I] = ((u64)sb << 32) |                                     \
                        ((u64)(16383 - (4 * g + I)) << 18) | (u64)(bc.C & 31u); \
                atomicAdd(&lh[(sb >> 16) - BUCK0], 1u);                       \
            }                                                                 \
        }
        KEY_C(x, 0) KEY_C(y, 1) KEY_C(z, 2) KEY_C(w, 3)
#undef KEY_C
        u64* wk = wk64 + (size_t)b * ANCH + 4 * g;
        ulonglong2 v01; v01.x = kv[0]; v01.y = kv[1];
        ulonglong2 v23; v23.x = kv[2]; v23.y = kv[3];
        *(ulonglong2*)&wk[0] = v01;
        *(ulonglong2*)&wk[2] = v23;
    }
    __syncthreads();
    u32* gh = histp + ((size_t)b * PBLK + blockIdx.x) * NBUCK;
    for (int i = t; i < NBUCK; i += 256) gh[i] = lh[i];
}

// ---------------- Phase B: fused threshold + matrix + fixpoint + emit ----------------
// 512 threads/image-block. Matrix: 1 row/thread in REGISTERS, column-outer,
// word-static accumulators (no LDS in the dependent chain beyond 3 broadcast
// reads per column, amortized over all 256 row-threads). Fixpoint: round-2's
// proven 4-word wave-0 ballot loop. Exact: A = {bucket >= taub} is
// suppression-closed (bucket-aligned), continuation covers underflow.
__global__ __launch_bounds__(512) void yolo_nms(const float* __restrict__ in,
                                                u64* __restrict__ wk64,
                                                const u32* __restrict__ histp,
                                                float* __restrict__ out) {
#pragma clang fp contract(off)
    const double M = (double)0.45f + 0x1p-26;
    int b = blockIdx.x, t = threadIdx.x;
    const float* inb = in + (size_t)b * (CHANS * ANCH);
    u64* gk = wk64 + (size_t)b * ANCH;

    __shared__ u32    hist[NBUCK];       // 1 KB
    __shared__ u64    ck[KTOP];          // 2 KB
    __shared__ float4 cb[KTOP];          // 4 KB
    __shared__ float  ca[KTOP];          // 1 KB
    __shared__ u64    SP[KTOP * 5];      // 10 KB (pad stride 5)
    __shared__ u64    selKey[KTOP];      // 2 KB
    __shared__ float  selb[MAXDET][5];   // 2 KB
    __shared__ u64    Smask[4];
    __shared__ u64    redm[8];
    __shared__ u32    wsum[8];
    __shared__ u32    bestP, shT, curA, staub, shK;
    __shared__ int    selTotS;

    float* outBox = out + (size_t)b * (MAXDET * 4);
    float* outCls = out + (size_t)(BATCH * MAXDET * 4) + b * MAXDET;
    float* outScr = out + (size_t)(BATCH * MAXDET * 5) + b * MAXDET;
    float* outNum = out + (size_t)(BATCH * MAXDET * 6) + b;

    if (t == 0) { bestP = 0u; curA = 0u; selTotS = 0; }

    // ---- sum the 33 per-block histogram partials (coalesced per j) ----
    const u32* ghp = histp + (size_t)b * PBLK * NBUCK;
    if (t < NBUCK) {
        u32 c = 0;
#pragma unroll
        for (int j = 0; j < PBLK; ++j) c += ghp[j * NBUCK + t];
        hist[t] = c;
    }
    __syncthreads();

    // ---- scan ranks (rank r = bucket 255-r, score-descending); pick taub/K/T ----
    u32 x = 0;
    if (t < NBUCK) {
        x = hist[255 - t];
#pragma unroll
        for (int d = 1; d < 64; d <<= 1) {
            u32 y = __shfl_up(x, d, 64);
            if ((t & 63) >= d) x += y;
        }
        if ((t & 63) == 63) wsum[t >> 6] = x;
    }
    __syncthreads();
    if (t < NBUCK) {
        u32 base = 0;
        for (int w = 0; w < (t >> 6); ++w) base += wsum[w];
        u32 inc = base + x;                       // inclusive prefix at rank t
        if (inc <= (u32)KTOP) atomicMax(&bestP, (inc << 8) | (u32)t);
        if (t == 255) shT = inc;
    }
    __syncthreads();
    if (t == 0) {
        u32 bp = bestP;
        if (bp == 0u) { shK = 0u; staub = (u32)NBUCK; }   // top bucket alone > KTOP
        else { shK = bp >> 8; staub = 255u - (bp & 255u); }
    }
    __syncthreads();
    u32 TB = BUCK0 + staub;                       // alive-in-A test: (k>>48) >= TB
    int K = (int)shK, T = (int)shT;

    // ---- compact A-keys (order-consistent within this kernel) ----
    for (int j = 0; j < 17; ++j) {
        int a = t + j * 512;
        if (a < ANCH) {
            u64 k = gk[a];
            if (k != 0ull && (u32)(k >> 48) >= TB) {
                u32 slot = atomicAdd(&curA, 1u);
                if (slot < (u32)KTOP) ck[slot] = k;
            }
        }
    }
    __syncthreads();
    for (int i = K + t; i < KTOP; i += 512) ck[i] = 0ull;
    __syncthreads();

    // ---- gather/recompute A-boxes ----
    if (t < KTOP) {
        u64 k = ck[t];
        float4 bb = make_float4(0.f, 0.f, 0.f, 0.f);
        if (k != 0ull) {
            int a = 16383 - (int)((k >> 18) & 0x3FFFull);
            bb = load_box(inb, a);
        }
        cb[t] = bb;
        ca[t] = (bb.z - bb.x) * (bb.w - bb.y);
    }
    __syncthreads();

    // ---- suppression matrix: 1 row per thread, row data in registers ----
    if (t < KTOP) {
        u64 kr = ck[t];
        float4 rb = cb[t];
        float rar = ca[t];
#pragma unroll
        for (int w = 0; w < 4; ++w) {
            u64 word = 0ull;
            int lo = w << 6;
            int hi = K - lo; if (hi > 64) hi = 64;
#pragma unroll 4
            for (int j2 = 0; j2 < hi; ++j2) {
                int i = lo + j2;
                u64 ki = ck[i];                   // broadcast reads
                float4 ob = cb[i];
                float oar = ca[i];
                if ((ki > kr) && iou_gt(ob.x, ob.y, ob.z, ob.w, oar,
                                        rb.x, rb.y, rb.z, rb.w, rar, M))
                    word |= 1ull << j2;
            }
            SP[t * 5 + w] = word;
        }
    }
    __syncthreads();

    // ---- ballot fixpoint over top-K (wave 0; 4-word; exact greedy) ----
    u64 S[4];
    S[0] = S[1] = S[2] = S[3] = 0ull;
    if (t < 64) {
        int L = t;
        u64 so0[4], so1[4], so2[4], so3[4];
#pragma unroll
        for (int w = 0; w < 4; ++w) {
            so0[w] = SP[(L      ) * 5 + w];
            so1[w] = SP[(L + 64 ) * 5 + w];
            so2[w] = SP[(L + 128) * 5 + w];
            so3[w] = SP[(L + 192) * 5 + w];
        }
        u64 U[4];
        U[0] = __ballot(ck[L      ] != 0ull);
        U[1] = __ballot(ck[L + 64 ] != 0ull);
        U[2] = __ballot(ck[L + 128] != 0ull);
        U[3] = __ballot(ck[L + 192] != 0ull);
        for (int it = 0; it < KTOP; ++it) {
            if (!(U[0] | U[1] | U[2] | U[3])) break;
            u64 D[4];
            {
                u64 p0 = (so0[0]&U[0])|(so0[1]&U[1])|(so0[2]&U[2])|(so0[3]&U[3]);
                u64 p1 = (so1[0]&U[0])|(so1[1]&U[1])|(so1[2]&U[2])|(so1[3]&U[3]);
                u64 p2 = (so2[0]&U[0])|(so2[1]&U[1])|(so2[2]&U[2])|(so2[3]&U[3]);
                u64 p3 = (so3[0]&U[0])|(so3[1]&U[1])|(so3[2]&U[2])|(so3[3]&U[3]);
                D[0] = __ballot(((U[0] >> L) & 1ull) && (p0 == 0ull));
                D[1] = __ballot(((U[1] >> L) & 1ull) && (p1 == 0ull));
                D[2] = __ballot(((U[2] >> L) & 1ull) && (p2 == 0ull));
                D[3] = __ballot(((U[3] >> L) & 1ull) && (p3 == 0ull));
            }
#pragma unroll
            for (int w = 0; w < 4; ++w) { S[w] |= D[w]; U[w] &= ~D[w]; }
            {
                u64 h0 = (so0[0]&D[0])|(so0[1]&D[1])|(so0[2]&D[2])|(so0[3]&D[3]);
                u64 h1 = (so1[0]&D[0])|(so1[1]&D[1])|(so1[2]&D[2])|(so1[3]&D[3]);
                u64 h2 = (so2[0]&D[0])|(so2[1]&D[1])|(so2[2]&D[2])|(so2[3]&D[3]);
                u64 h3 = (so3[0]&D[0])|(so3[1]&D[1])|(so3[2]&D[2])|(so3[3]&D[3]);
                U[0] &= ~__ballot(((U[0] >> L) & 1ull) && (h0 != 0ull));
                U[1] &= ~__ballot(((U[1] >> L) & 1ull) && (h1 != 0ull));
                U[2] &= ~__ballot(((U[2] >> L) & 1ull) && (h2 != 0ull));
                U[3] &= ~__ballot(((U[3] >> L) & 1ull) && (h3 != 0ull));
            }
        }
        if (L == 0) {
            Smask[0] = S[0]; Smask[1] = S[1]; Smask[2] = S[2]; Smask[3] = S[3];
            selTotS = (int)(__popcll(S[0]) + __popcll(S[1]) + __popcll(S[2]) + __popcll(S[3]));
        }
    }
    __syncthreads();

    int sTot = selTotS;
    int s = sTot < MAXDET ? sTot : MAXDET;

    // ---- dense selected-key list + emission in exact key order (wave 0) ----
    if (t < 64) {
        int L = t, kb = 0;
#pragma unroll
        for (int w = 0; w < 4; ++w) {
            u64 Sw = S[w];
            if ((Sw >> L) & 1ull) {
                int r = kb + (int)__popcll(Sw & ((1ull << L) - 1ull));
                selKey[r] = ck[(w << 6) + L];
            }
            kb += (int)__popcll(Sw);
        }
        // LDS writes by this wave are ordered before its own reads below
#pragma unroll
        for (int w = 0; w < 4; ++w) {
            if ((S[w] >> L) & 1ull) {
                u64 myk = ck[(w << 6) + L];
                int pos = 0;
                for (int j = 0; j < sTot; ++j) pos += (selKey[j] > myk) ? 1 : 0;
                if (pos < MAXDET) {
                    int a = 16383 - (int)((myk >> 18) & 0x3FFFull);
                    float4 bb = load_box(inb, a);
                    outScr[pos] = __uint_as_float((u32)(myk >> 32));
                    outCls[pos] = (float)((u32)myk & 31u);
                    outBox[pos * 4 + 0] = bb.x; outBox[pos * 4 + 1] = bb.y;
                    outBox[pos * 4 + 2] = bb.z; outBox[pos * 4 + 3] = bb.w;
                    selb[pos][0] = bb.x; selb[pos][1] = bb.y; selb[pos][2] = bb.z;
                    selb[pos][3] = bb.w; selb[pos][4] = (bb.z - bb.x) * (bb.w - bb.y);
                }
            }
        }
    }
    __syncthreads();

    // ---- exact continuation over sub-threshold keys (rare path) ----
    if (s < MAXDET && T > K) {
        for (int i = t; i < ANCH; i += 512) {    // de-dup A + prekill vs selected
            u64 k = gk[i];
            if (k != 0ull) {
                if ((u32)(k >> 48) >= TB) { gk[i] = 0ull; continue; }
                int a = 16383 - (int)((k >> 18) & 0x3FFFull);
                float4 bb = load_box(inb, a);
                float ar = (bb.z - bb.x) * (bb.w - bb.y);
                for (int j = 0; j < s; ++j) {
                    if (iou_gt(selb[j][0], selb[j][1], selb[j][2], selb[j][3], selb[j][4],
                               bb.x, bb.y, bb.z, bb.w, ar, M)) { gk[i] = 0ull; break; }
                }
            }
        }
        __syncthreads();
        while (s < MAXDET) {
            u64 best = 0ull;
            for (int i = t; i < ANCH; i += 512) { u64 k = gk[i]; if (k > best) best = k; }
#pragma unroll
            for (int sh = 1; sh < 64; sh <<= 1) {
                u64 o = __shfl_xor(best, sh, 64);
                if (o > best) best = o;
            }
            if ((t & 63) == 0) redm[t >> 6] = best;
            __syncthreads();
            best = redm[0];
            for (int w = 1; w < 8; ++w) if (redm[w] > best) best = redm[w];
            if (best == 0ull) break;
            int a = 16383 - (int)((best >> 18) & 0x3FFFull);
            float4 nb = load_box(inb, a);
            float nar = (nb.z - nb.x) * (nb.w - nb.y);
            if (t == 0) {
                outScr[s] = __uint_as_float((u32)(best >> 32));
                outCls[s] = (float)((u32)best & 31u);
                outBox[s * 4 + 0] = nb.x; outBox[s * 4 + 1] = nb.y;
                outBox[s * 4 + 2] = nb.z; outBox[s * 4 + 3] = nb.w;
            }
            for (int i = t; i < ANCH; i += 512) {
                u64 k = gk[i];
                if (k != 0ull) {
                    if (k == best) gk[i] = 0ull;
                    else {
                        int a2 = 16383 - (int)((k >> 18) & 0x3FFFull);
                        float4 bb = load_box(inb, a2);
                        float ar = (bb.z - bb.x) * (bb.w - bb.y);
                        if (iou_gt(nb.x, nb.y, nb.z, nb.w, nar,
                                   bb.x, bb.y, bb.z, bb.w, ar, M)) gk[i] = 0ull;
                    }
                }
            }
            ++s;
            __syncthreads();
        }
    }

    for (int q = s + t; q < MAXDET; q += 512) {
        outScr[q] = 0.f; outCls[q] = 0.f;
        outBox[q * 4 + 0] = 0.f; outBox[q * 4 + 1] = 0.f;
        outBox[q * 4 + 2] = 0.f; outBox[q * 4 + 3] = 0.f;
    }
    if (t == 0) *outNum = (float)s;
}

extern "C" void kernel_launch(void* const* d_in, const int* in_sizes, int n_in,
                              void* d_out, int out_size, void* d_ws, size_t ws_size,
                              hipStream_t stream) {
    const float* in = (const float*)d_in[0];
    float* out = (float*)d_out;
    // workspace (~6.5 MB):
    //   wk64  u64[64*8400]           4,300,800 B
    //   histp u32[64*33*256]         2,162,688 B  (per-block partials, fully
    //                                              overwritten each launch)
    char* w = (char*)d_ws;
    u64* wk64  = (u64*)w;
    u32* histp = (u32*)(w + 4300800);

    yolo_prep<<<dim3(PBLK, BATCH), 256, 0, stream>>>(in, wk64, histp);
    yolo_nms<<<BATCH, 512, 0, stream>>>(in, wk64, histp, out);
}

// Round 9
// 212.277 us; speedup vs baseline: 4.9136x; 4.9136x over previous
//
#include <hip/hip_runtime.h>

#define BATCH   64
#define CHANS   36
#define ANCH    8400
#define NCLS    32
#define MAXDET  100
#define CONF    0.25f
#define KTOP    512             // matrix region (bucket-aligned cutoff K <= KTOP)
#define NBUCK   2048
#define BUCK13  (0x3E800000u >> 13)   // bucket base: 8192-ulp buckets over [0.25,1.0)
#define PBLK    33              // prep blocks per image (ceil(2100/64))

typedef unsigned long long u64;
typedef unsigned int       u32;

// exact ref IoU-threshold compare: for uni>0, RN(inter/uni) > 0.45f <=> inter > M*uni
// (a = suppressor box, matching reference op order; f32 ops, no contraction)
__device__ __forceinline__ bool iou_gt(float ay1, float ax1, float ay2, float ax2, float aar,
                                       float by1, float bx1, float by2, float bx2, float bar,
                                       double M) {
#pragma clang fp contract(off)
    float iy1 = fmaxf(ay1, by1), ix1 = fmaxf(ax1, bx1);
    float iy2 = fminf(ay2, by2), ix2 = fminf(ax2, bx2);
    float inter = fmaxf(iy2 - iy1, 0.f) * fmaxf(ix2 - ix1, 0.f);
    float uni = (aar + bar) - inter;
    return (double)inter > M * (double)uni;
}

// recompute clipped corner box for anchor a (bit-identical to reference)
__device__ __forceinline__ float4 load_box(const float* __restrict__ inb, int a) {
#pragma clang fp contract(off)
    float xc = inb[0 * ANCH + a], yc = inb[1 * ANCH + a];
    float w  = inb[2 * ANCH + a], h  = inb[3 * ANCH + a];
    float4 r;
    r.x = fminf(fmaxf(yc - h * 0.5f, 0.f), 1.f);
    r.y = fminf(fmaxf(xc - w * 0.5f, 0.f), 1.f);
    r.z = fminf(fmaxf(yc + h * 0.5f, 0.f), 1.f);
    r.w = fminf(fmaxf(xc + w * 0.5f, 0.f), 1.f);
    return r;
}

// ---------------- Phase A: prep (keys only), 4 threads per float4-group ----------------
// Lane layout: sub = lane&15 picks group-in-16, q = lane>>4 picks the 8-class
// quarter; xor-shuffles over lane bits 16/32 combine quarters (tie -> lower
// class = np.argmax-first). 2112 blocks -> high TLP; no LDS, no barrier.
__global__ __launch_bounds__(256) void yolo_prep(const float* __restrict__ in,
                                                 u64* __restrict__ wk64) {
#pragma clang fp contract(off)
    const int G = ANCH / 4;             // 2100
    int t = threadIdx.x, b = blockIdx.y;
    int lane = t & 63, wv = t >> 6;
    int sub = lane & 15, q = lane >> 4;
    int g = blockIdx.x * 64 + wv * 16 + sub;
    bool act = (g < G);

    const float4* p = (const float4*)(in + (size_t)b * (CHANS * ANCH));
    float4 bs = make_float4(-1e30f, -1e30f, -1e30f, -1e30f);
    uint4  bc = make_uint4(0, 0, 0, 0);
    if (act) {
        int c0 = q * 8;
        bs = p[(4 + c0) * G + g];
        bc = make_uint4((u32)c0, (u32)c0, (u32)c0, (u32)c0);
#pragma unroll
        for (int k = 1; k < 8; ++k) {
            float4 v = p[(4 + c0 + k) * G + g];
            u32 c = (u32)(c0 + k);
            if (v.x > bs.x) { bs.x = v.x; bc.x = c; }   // strict >: first index (np.argmax)
            if (v.y > bs.y) { bs.y = v.y; bc.y = c; }
            if (v.z > bs.z) { bs.z = v.z; bc.z = c; }
            if (v.w > bs.w) { bs.w = v.w; bc.w = c; }
        }
    }
#pragma unroll
    for (int d = 16; d < 64; d <<= 1) {
        float sx = __shfl_xor(bs.x, d, 64); u32 cx = __shfl_xor(bc.x, d, 64);
        float sy = __shfl_xor(bs.y, d, 64); u32 cy = __shfl_xor(bc.y, d, 64);
        float sz = __shfl_xor(bs.z, d, 64); u32 cz = __shfl_xor(bc.z, d, 64);
        float sw = __shfl_xor(bs.w, d, 64); u32 cw = __shfl_xor(bc.w, d, 64);
        if (sx > bs.x || (sx == bs.x && cx < bc.x)) { bs.x = sx; bc.x = cx; }
        if (sy > bs.y || (sy == bs.y && cy < bc.y)) { bs.y = sy; bc.y = cy; }
        if (sz > bs.z || (sz == bs.z && cz < bc.z)) { bs.z = sz; bc.z = cz; }
        if (sw > bs.w || (sw == bs.w && cw < bc.w)) { bs.w = sw; bc.w = cw; }
    }
    if (act && q == 0) {
        u64 kv[4];
#define KEY_C(C, I)                                                           \
        {                                                                     \
            kv[I] = 0ull;                                                     \
            if (bs.C >= CONF) {                                               \
                u32 sb = __float_as_uint(bs.C);                               \
                kv[I] = ((u64)sb << 32) |                                     \
                        ((u64)(16383 - (4 * g + I)) << 18) | (u64)(bc.C & 31u); \
            }                                                                 \
        }
        KEY_C(x, 0) KEY_C(y, 1) KEY_C(z, 2) KEY_C(w, 3)
#undef KEY_C
        u64* wk = wk64 + (size_t)b * ANCH + 4 * g;
        ulonglong2 v01; v01.x = kv[0]; v01.y = kv[1];
        ulonglong2 v23; v23.x = kv[2]; v23.y = kv[3];
        *(ulonglong2*)&wk[0] = v01;
        *(ulonglong2*)&wk[2] = v23;
    }
}

// ---------------- Phase B: hist + threshold + matrix + fixpoint + emit ----------------
// 512 threads/image. Keys loaded once to registers; LDS hist (2048 buckets,
// top bucket ~130 on max-of-32-uniform data); scan -> bucket-aligned taub with
// K = count(bucket >= taub) <= KTOP; compact from registers; register-row
// suppression matrix; 8-word wave-0 ballot fixpoint (exact greedy); rank-emit.
// A = {bucket >= taub} is suppression-closed (exactness); continuation covers
// the K=0 / underflow cases exactly (HW-validated in round 8).
__global__ __launch_bounds__(512) void yolo_nms(const float* __restrict__ in,
                                                u64* __restrict__ wk64,
                                                float* __restrict__ out) {
#pragma clang fp contract(off)
    const double M = (double)0.45f + 0x1p-26;
    int b = blockIdx.x, t = threadIdx.x;
    const float* inb = in + (size_t)b * (CHANS * ANCH);
    u64* gk = wk64 + (size_t)b * ANCH;

    __shared__ u32    hist[NBUCK];       // 8 KB
    __shared__ u64    ck[KTOP];          // 4 KB
    __shared__ float4 cb[KTOP];          // 8 KB
    __shared__ float  ca[KTOP];          // 2 KB
    __shared__ u64    SP[KTOP * 9];      // 36.9 KB (pad stride 9)
    __shared__ u64    selKey[KTOP];      // 4 KB
    __shared__ float  selb[MAXDET][5];   // 2 KB
    __shared__ u64    redm[8];
    __shared__ u32    wsum[8];
    __shared__ u32    bestP, shT, curA, staub, shK;
    __shared__ int    selTotS;

    float* outBox = out + (size_t)b * (MAXDET * 4);
    float* outCls = out + (size_t)(BATCH * MAXDET * 4) + b * MAXDET;
    float* outScr = out + (size_t)(BATCH * MAXDET * 5) + b * MAXDET;
    float* outNum = out + (size_t)(BATCH * MAXDET * 6) + b;

    if (t == 0) { bestP = 0u; curA = 0u; selTotS = 0; }
    for (int i = t; i < NBUCK; i += 512) hist[i] = 0u;
    __syncthreads();

    // ---- load keys to registers + LDS histogram ----
    u64 kk[17];
#pragma unroll
    for (int j = 0; j < 17; ++j) {
        int a = t + j * 512;
        u64 k = (a < ANCH) ? gk[a] : 0ull;
        kk[j] = k;
        if (k != 0ull) atomicAdd(&hist[(u32)(k >> 45) - BUCK13], 1u);
    }
    __syncthreads();

    // ---- scan ranks (rank r = bucket 2047-r, score-descending); pick taub/K/T ----
    u32 c4[4], sloc[4];
    u32 run = 0;
#pragma unroll
    for (int q = 0; q < 4; ++q) {
        int r = t * 4 + q;
        c4[q] = hist[2047 - r];
        run += c4[q];
        sloc[q] = run;
    }
    u32 Su = run, x = Su;
#pragma unroll
    for (int d = 1; d < 64; d <<= 1) {
        u32 y = __shfl_up(x, d, 64);
        if ((t & 63) >= d) x += y;
    }
    if ((t & 63) == 63) wsum[t >> 6] = x;
    __syncthreads();
    u32 base = 0;
    for (int w = 0; w < (t >> 6); ++w) base += wsum[w];
    u32 excl = base + x - Su;            // exclusive prefix (by rank) of my 4-rank group
#pragma unroll
    for (int q = 0; q < 4; ++q) {
        u32 inc = excl + sloc[q];
        if (inc <= (u32)KTOP) atomicMax(&bestP, (inc << 11) | (u32)(t * 4 + q));
    }
    if (t == 511) shT = excl + Su;
    __syncthreads();
    if (t == 0) {
        u32 bp = bestP;
        if (bp == 0u) { shK = 0u; staub = (u32)NBUCK; }   // top bucket alone > KTOP
        else { shK = bp >> 11; staub = 2047u - (bp & 0x7FFu); }
    }
    __syncthreads();
    u32 TB = BUCK13 + staub;             // alive-in-A test: (k>>45) >= TB
    int K = (int)shK, T = (int)shT;

    // ---- compact A-keys from registers ----
#pragma unroll
    for (int j = 0; j < 17; ++j) {
        u64 k = kk[j];
        if (k != 0ull && (u32)(k >> 45) >= TB) {
            u32 slot = atomicAdd(&curA, 1u);
            if (slot < (u32)KTOP) ck[slot] = k;   // slot < K by construction
        }
    }
    __syncthreads();
    for (int i = K + t; i < KTOP; i += 512) ck[i] = 0ull;
    __syncthreads();

    // ---- gather/recompute A-boxes (one row per thread) ----
    {
        u64 k = ck[t];
        float4 bb = make_float4(0.f, 0.f, 0.f, 0.f);
        if (k != 0ull) {
            int a = 16383 - (int)((k >> 18) & 0x3FFFull);
            bb = load_box(inb, a);
        }
        cb[t] = bb;
        ca[t] = (bb.z - bb.x) * (bb.w - bb.y);
    }
    __syncthreads();

    // ---- suppression matrix: 1 row per thread, row data in registers ----
    {
        u64 kr = ck[t];
        float4 rb = cb[t];
        float rar = ca[t];
#pragma unroll
        for (int w = 0; w < 8; ++w) {
            u64 word = 0ull;
            int lo = w << 6;
            int hi = K - lo; if (hi > 64) hi = 64;
#pragma unroll 4
            for (int j2 = 0; j2 < hi; ++j2) {
                int i = lo + j2;
                u64 ki = ck[i];                   // broadcast reads
                float4 ob = cb[i];
                if ((ki > kr) && iou_gt(ob.x, ob.y, ob.z, ob.w, ca[i],
                                        rb.x, rb.y, rb.z, rb.w, rar, M))
                    word |= 1ull << j2;
            }
            SP[t * 9 + w] = word;
        }
    }
    __syncthreads();

    // ---- ballot fixpoint over top-K (wave 0; 8 words; exact greedy) ----
    u64 S[8];
#pragma unroll
    for (int w = 0; w < 8; ++w) S[w] = 0ull;
    if (t < 64) {
        int L = t;
        u64 U[8];
#pragma unroll
        for (int w = 0; w < 8; ++w) U[w] = __ballot(ck[(w << 6) + L] != 0ull);
        for (int it = 0; it < KTOP; ++it) {
            if (!(U[0] | U[1] | U[2] | U[3] | U[4] | U[5] | U[6] | U[7])) break;
            u64 D[8];
#pragma unroll
            for (int w = 0; w < 8; ++w) {
                const u64* rm = &SP[((w << 6) + L) * 9];
                u64 pend = (rm[0] & U[0]) | (rm[1] & U[1]) | (rm[2] & U[2]) | (rm[3] & U[3])
                         | (rm[4] & U[4]) | (rm[5] & U[5]) | (rm[6] & U[6]) | (rm[7] & U[7]);
                D[w] = __ballot(((U[w] >> L) & 1ull) && (pend == 0ull));
            }
#pragma unroll
            for (int w = 0; w < 8; ++w) { S[w] |= D[w]; U[w] &= ~D[w]; }
#pragma unroll
            for (int w = 0; w < 8; ++w) {
                const u64* rm = &SP[((w << 6) + L) * 9];
                u64 hit = (rm[0] & D[0]) | (rm[1] & D[1]) | (rm[2] & D[2]) | (rm[3] & D[3])
                        | (rm[4] & D[4]) | (rm[5] & D[5]) | (rm[6] & D[6]) | (rm[7] & D[7]);
                U[w] &= ~__ballot(((U[w] >> L) & 1ull) && (hit != 0ull));
            }
        }
        if (t == 0) {
            int c = 0;
#pragma unroll
            for (int w = 0; w < 8; ++w) c += (int)__popcll(S[w]);
            selTotS = c;
        }
    }
    __syncthreads();

    int sTot = selTotS;
    int s = sTot < MAXDET ? sTot : MAXDET;

    // ---- dense selected-key list + emission in exact key order (wave 0) ----
    if (t < 64) {
        int L = t, kb = 0;
#pragma unroll
        for (int w = 0; w < 8; ++w) {
            u64 Sw = S[w];
            if ((Sw >> L) & 1ull) {
                int r = kb + (int)__popcll(Sw & ((1ull << L) - 1ull));
                selKey[r] = ck[(w << 6) + L];
            }
            kb += (int)__popcll(Sw);
        }
#pragma unroll
        for (int w = 0; w < 8; ++w) {
            if ((S[w] >> L) & 1ull) {
                u64 myk = ck[(w << 6) + L];
                int pos = 0;
                for (int j = 0; j < sTot; ++j) pos += (selKey[j] > myk) ? 1 : 0;
                if (pos < MAXDET) {
                    int a = 16383 - (int)((myk >> 18) & 0x3FFFull);
                    float4 bb = load_box(inb, a);
                    outScr[pos] = __uint_as_float((u32)(myk >> 32));
                    outCls[pos] = (float)((u32)myk & 31u);
                    outBox[pos * 4 + 0] = bb.x; outBox[pos * 4 + 1] = bb.y;
                    outBox[pos * 4 + 2] = bb.z; outBox[pos * 4 + 3] = bb.w;
                    selb[pos][0] = bb.x; selb[pos][1] = bb.y; selb[pos][2] = bb.z;
                    selb[pos][3] = bb.w; selb[pos][4] = (bb.z - bb.x) * (bb.w - bb.y);
                }
            }
        }
    }
    __syncthreads();

    // ---- exact continuation over sub-threshold keys (rare path; HW-validated) ----
    if (s < MAXDET && T > K) {
        for (int i = t; i < ANCH; i += 512) {    // de-dup A + prekill vs selected
            u64 k = gk[i];
            if (k != 0ull) {
                if ((u32)(k >> 45) >= TB) { gk[i] = 0ull; continue; }
                int a = 16383 - (int)((k >> 18) & 0x3FFFull);
                float4 bb = load_box(inb, a);
                float ar = (bb.z - bb.x) * (bb.w - bb.y);
                for (int j = 0; j < s; ++j) {
                    if (iou_gt(selb[j][0], selb[j][1], selb[j][2], selb[j][3], selb[j][4],
                               bb.x, bb.y, bb.z, bb.w, ar, M)) { gk[i] = 0ull; break; }
                }
            }
        }
        __syncthreads();
        while (s < MAXDET) {
            u64 best = 0ull;
            for (int i = t; i < ANCH; i += 512) { u64 k = gk[i]; if (k > best) best = k; }
#pragma unroll
            for (int sh = 1; sh < 64; sh <<= 1) {
                u64 o = __shfl_xor(best, sh, 64);
                if (o > best) best = o;
            }
            if ((t & 63) == 0) redm[t >> 6] = best;
            __syncthreads();
            best = redm[0];
            for (int w = 1; w < 8; ++w) if (redm[w] > best) best = redm[w];
            if (best == 0ull) break;
            int a = 16383 - (int)((best >> 18) & 0x3FFFull);
            float4 nb = load_box(inb, a);
            float nar = (nb.z - nb.x) * (nb.w - nb.y);
            if (t == 0) {
                outScr[s] = __uint_as_float((u32)(best >> 32));
                outCls[s] = (float)((u32)best & 31u);
                outBox[s * 4 + 0] = nb.x; outBox[s * 4 + 1] = nb.y;
                outBox[s * 4 + 2] = nb.z; outBox[s * 4 + 3] = nb.w;
            }
            for (int i = t; i < ANCH; i += 512) {
                u64 k = gk[i];
                if (k != 0ull) {
                    if (k == best) gk[i] = 0ull;
                    else {
                        int a2 = 16383 - (int)((k >> 18) & 0x3FFFull);
                        float4 bb = load_box(inb, a2);
                        float ar = (bb.z - bb.x) * (bb.w - bb.y);
                        if (iou_gt(nb.x, nb.y, nb.z, nb.w, nar,
                                   bb.x, bb.y, bb.z, bb.w, ar, M)) gk[i] = 0ull;
                    }
                }
            }
            ++s;
            __syncthreads();
        }
    }

    for (int q = s + t; q < MAXDET; q += 512) {
        outScr[q] = 0.f; outCls[q] = 0.f;
        outBox[q * 4 + 0] = 0.f; outBox[q * 4 + 1] = 0.f;
        outBox[q * 4 + 2] = 0.f; outBox[q * 4 + 3] = 0.f;
    }
    if (t == 0) *outNum = (float)s;
}

extern "C" void kernel_launch(void* const* d_in, const int* in_sizes, int n_in,
                              void* d_out, int out_size, void* d_ws, size_t ws_size,
                              hipStream_t stream) {
    const float* in = (const float*)d_in[0];
    float* out = (float*)d_out;
    // workspace: wk64 u64[64*8400] = 4,300,800 B (fully overwritten each launch)
    u64* wk64 = (u64*)d_ws;

    yolo_prep<<<dim3(PBLK, BATCH), 256, 0, stream>>>(in, wk64);
    yolo_nms<<<BATCH, 512, 0, stream>>>(in, wk64, out);
}